// Round 1
// baseline (5726.456 us; speedup 1.0000x reference)
//
#include <hip/hip_runtime.h>
#include <hip/hip_bf16.h>

// Problem: B=4, T=1024, C=1024, H=16, D=64, MAX_LEN=1024, NPOS=2047
// Pipeline:
//   cvt x,qkv_w,proj_w -> bf16 | table_reduce rel_pos_emb -> (2047,16)
//   gemm_bt<0>: qkv = x @ qkv_w^T + b  -> scatter bf16 (3,B,H,T,D)
//   attn: flash-style causal softmax w/ rel-pos bias -> y (B,T,C) bf16
//   gemm_bt<1>: out = y @ proj_w^T + b -> fp32 d_out
//
// Workspace layout (bytes):
//   xb   @ 0         : 4096x1024 bf16  (8 MB)
//   wb   @ 8388608   : 3072x1024 bf16  (6 MB)
//   pwb  @ 14680064  : 1024x1024 bf16  (2 MB)
//   table@ 16777216  : 2047x16 f32     (128 KB)
//   qkvb @ 16908288  : (3,4,16,1024,64) bf16 (24 MB)
//   y    @ 42074112  : 4096x1024 bf16  (8 MB)
// total ~48.1 MB

typedef __bf16 bf16x8 __attribute__((ext_vector_type(8)));
typedef float f32x4 __attribute__((ext_vector_type(4)));

__device__ __forceinline__ float bf2f(unsigned short u) {
    return __uint_as_float(((unsigned)u) << 16);
}
__device__ __forceinline__ unsigned short f2bf(float f) {
    __hip_bfloat16 h = __float2bfloat16(f);
    return *reinterpret_cast<unsigned short*>(&h);
}

// ---------------- fp32 -> bf16 conversion ----------------
__global__ __launch_bounds__(256) void cvt_f32_bf16(const float* __restrict__ in,
                                                    unsigned short* __restrict__ out, int n) {
    int i = (blockIdx.x * 256 + threadIdx.x) * 4;
    if (i < n) {
        float4 v = *(const float4*)(in + i);
        out[i]     = f2bf(v.x);
        out[i + 1] = f2bf(v.y);
        out[i + 2] = f2bf(v.z);
        out[i + 3] = f2bf(v.w);
    }
}

// ---------------- rel_pos_emb (2047,1024) -> table (2047,16) ----------------
// block p: thread t loads cols t, t+256, t+512, t+768; partial k belongs to
// h = t/64 + 4k = wave + 4k -> 4 full-wave shuffle reductions per wave.
__global__ __launch_bounds__(256) void table_reduce(const float* __restrict__ rel,
                                                    float* __restrict__ table) {
    const int p = blockIdx.x;
    const int tid = threadIdx.x, lane = tid & 63, wave = tid >> 6;
    const float* r = rel + (size_t)p * 1024;
    float s[4];
#pragma unroll
    for (int k = 0; k < 4; ++k) s[k] = r[tid + 256 * k];
#pragma unroll
    for (int k = 0; k < 4; ++k) {
        float v = s[k];
        for (int o = 32; o; o >>= 1) v += __shfl_xor(v, o, 64);
        if (lane == 0) table[p * 16 + wave + 4 * k] = v;
    }
}

// ---------------- bf16 MFMA GEMM: C[m,n] = sum_k A[m,k]*B[n,k] + bias[n] ----------------
// 64x64 tile, BK=32, 4 waves each computing 2x2 16x16 MFMA tiles.
// EPI=0: scatter bf16 into (3,B,H,T,D).  EPI=1: fp32 row-major out.
template <int EPI>
__global__ __launch_bounds__(256) void gemm_bt(const unsigned short* __restrict__ A,
                                               const unsigned short* __restrict__ Bm,
                                               const float* __restrict__ bias,
                                               unsigned short* __restrict__ outb,
                                               float* __restrict__ outf,
                                               int M, int N, int K) {
    __shared__ __attribute__((aligned(16))) unsigned short As[64][40];  // stride 40 shorts = 80B (16B-mult)
    __shared__ __attribute__((aligned(16))) unsigned short Bs[64][40];
    const int bm = blockIdx.x * 64, bn = blockIdx.y * 64;
    const int tid = threadIdx.x, lane = tid & 63, wave = tid >> 6;
    const int wr = wave & 1, wc = wave >> 1;
    const int quad = lane >> 4, lm = lane & 15;
    const int srow = tid >> 2, scol = (tid & 3) * 8;

    f32x4 acc00 = {0.f, 0.f, 0.f, 0.f};
    f32x4 acc01 = {0.f, 0.f, 0.f, 0.f};
    f32x4 acc10 = {0.f, 0.f, 0.f, 0.f};
    f32x4 acc11 = {0.f, 0.f, 0.f, 0.f};

    const unsigned short* Aptr = A + (size_t)(bm + srow) * K + scol;
    const unsigned short* Bptr = Bm + (size_t)(bn + srow) * K + scol;

    for (int kk = 0; kk < K; kk += 32) {
        __syncthreads();
        *(int4*)(&As[srow][scol]) = *(const int4*)(Aptr + kk);
        *(int4*)(&Bs[srow][scol]) = *(const int4*)(Bptr + kk);
        __syncthreads();
        // A frag: A[m=lm][k=quad*8+i]; B frag: B[n=lm][k=quad*8+i]
        bf16x8 a0 = *(const bf16x8*)(&As[32 * wr + lm][quad * 8]);
        bf16x8 a1 = *(const bf16x8*)(&As[32 * wr + 16 + lm][quad * 8]);
        bf16x8 b0 = *(const bf16x8*)(&Bs[32 * wc + lm][quad * 8]);
        bf16x8 b1 = *(const bf16x8*)(&Bs[32 * wc + 16 + lm][quad * 8]);
        acc00 = __builtin_amdgcn_mfma_f32_16x16x32_bf16(a0, b0, acc00, 0, 0, 0);
        acc01 = __builtin_amdgcn_mfma_f32_16x16x32_bf16(a0, b1, acc01, 0, 0, 0);
        acc10 = __builtin_amdgcn_mfma_f32_16x16x32_bf16(a1, b0, acc10, 0, 0, 0);
        acc11 = __builtin_amdgcn_mfma_f32_16x16x32_bf16(a1, b1, acc11, 0, 0, 0);
    }

    // C/D layout (verified): col = lane&15, row = (lane>>4)*4 + reg
    f32x4 accs[2][2] = {{acc00, acc01}, {acc10, acc11}};
#pragma unroll
    for (int r = 0; r < 2; ++r)
#pragma unroll
        for (int c = 0; c < 2; ++c)
#pragma unroll
            for (int i = 0; i < 4; ++i) {
                const int row = bm + 32 * wr + 16 * r + quad * 4 + i;
                const int col = bn + 32 * wc + 16 * c + lm;
                const float v = accs[r][c][i] + bias[col];
                if (EPI == 0) {
                    // n -> (s,h,d); m -> (b,t); store (3,B,H,T,D) bf16
                    const int b = row >> 10, t = row & 1023;
                    const int s3 = col >> 10, rem = col & 1023;
                    const int h = rem >> 6, d = rem & 63;
                    const size_t off = ((((size_t)s3 * 4 + b) * 16 + h) * 1024 + t) * 64 + d;
                    outb[off] = f2bf(v);
                } else {
                    outf[(size_t)row * N + col] = v;
                }
            }
}

// ---------------- flash-style causal attention w/ rel-pos bias ----------------
// grid (B*H, T/64), block 256 = 4 waves. Wave w owns queries qb+16w..+15.
// Per key tile of 64: lane j computes scores for 4 queries at a time
// (register blocking amortizes Kt/Vt LDS traffic 4x), online softmax,
// P broadcast through per-wave LDS buffer, out accumulated per-lane (lane=d).
__global__ __launch_bounds__(256) void attn_kernel(const unsigned short* __restrict__ qkvb,
                                                   const float* __restrict__ table,
                                                   unsigned short* __restrict__ y) {
    const int bh = blockIdx.x, b = bh >> 4, h = bh & 15;
    const int qb = blockIdx.y * 64;
    const int tid = threadIdx.x, lane = tid & 63, wave = tid >> 6;

    __shared__ __attribute__((aligned(16))) float Qt[64][68];  // stride 68 f32 = 272B (16B-mult)
    __shared__ __attribute__((aligned(16))) float Kt[64][68];
    __shared__ __attribute__((aligned(16))) float Vt[64][68];
    __shared__ __attribute__((aligned(16))) float pb[4][64][4];
    __shared__ float tb[1088];

    const size_t plane = (size_t)1024 * 64;
    const unsigned short* Qg = qkvb + ((size_t)(0 * 4 + b) * 16 + h) * plane;
    const unsigned short* Kg = qkvb + ((size_t)(1 * 4 + b) * 16 + h) * plane;
    const unsigned short* Vg = qkvb + ((size_t)(2 * 4 + b) * 16 + h) * plane;

    // stage Q tile (bf16 -> f32)
    for (int i = tid; i < 512; i += 256) {
        const int r = i >> 3, c8 = (i & 7) << 3;
        int4 q4 = *(const int4*)(Qg + (size_t)(qb + r) * 64 + c8);
        const unsigned short* us = (const unsigned short*)&q4;
#pragma unroll
        for (int t = 0; t < 8; ++t) Qt[r][c8 + t] = bf2f(us[t]);
    }
    // stage bias-table window: rows 960 .. 960+qb+126 of column h; use tb[q-j+63]
    const int tbn = qb + 127;
    for (int i = tid; i < tbn; i += 256) tb[i] = table[(960 + i) * 16 + h];

    float mi[16], li[16], ou[16];
#pragma unroll
    for (int i = 0; i < 16; ++i) { mi[i] = -1e30f; li[i] = 0.f; ou[i] = 0.f; }

    const int ktiles = qb / 64 + 1;  // tiles 0..qb/64 (kt*64 <= qb <= every q in block)
    for (int kt = 0; kt < ktiles; ++kt) {
        __syncthreads();
        for (int i = tid; i < 512; i += 256) {
            const int r = i >> 3, c8 = (i & 7) << 3;
            int4 k4 = *(const int4*)(Kg + (size_t)(kt * 64 + r) * 64 + c8);
            int4 v4 = *(const int4*)(Vg + (size_t)(kt * 64 + r) * 64 + c8);
            const unsigned short* ku = (const unsigned short*)&k4;
            const unsigned short* vu = (const unsigned short*)&v4;
#pragma unroll
            for (int t = 0; t < 8; ++t) {
                Kt[r][c8 + t] = bf2f(ku[t]);
                Vt[r][c8 + t] = bf2f(vu[t]);
            }
        }
        __syncthreads();
        const int j = kt * 64 + lane;
#pragma unroll
        for (int g = 0; g < 4; ++g) {
            const int q0 = qb + wave * 16 + g * 4;
            const int qr0 = wave * 16 + g * 4;
            float sc[4] = {0.f, 0.f, 0.f, 0.f};
            for (int d4 = 0; d4 < 64; d4 += 4) {
                float4 kv = *(const float4*)(&Kt[lane][d4]);
#pragma unroll
                for (int qq = 0; qq < 4; ++qq) {
                    float4 qv = *(const float4*)(&Qt[qr0 + qq][d4]);
                    sc[qq] = fmaf(qv.x, kv.x, sc[qq]);
                    sc[qq] = fmaf(qv.y, kv.y, sc[qq]);
                    sc[qq] = fmaf(qv.z, kv.z, sc[qq]);
                    sc[qq] = fmaf(qv.w, kv.w, sc[qq]);
                }
            }
            float al[4], pv4[4];
#pragma unroll
            for (int qq = 0; qq < 4; ++qq) {
                const int q = q0 + qq;
                const bool valid = (j <= q);
                const float s = valid ? fmaf(sc[qq], 0.125f, tb[q - j + 63]) : -1e30f;
                float mx = s;
                for (int o = 32; o; o >>= 1) mx = fmaxf(mx, __shfl_xor(mx, o, 64));
                const float mold = mi[g * 4 + qq];
                const float mnew = fmaxf(mold, mx);
                const float p = valid ? __expf(s - mnew) : 0.f;
                float ps = p;
                for (int o = 32; o; o >>= 1) ps += __shfl_xor(ps, o, 64);
                const float alpha = __expf(mold - mnew);  // mold=-1e30 -> 0, no NaN
                li[g * 4 + qq] = li[g * 4 + qq] * alpha + ps;
                mi[g * 4 + qq] = mnew;
                al[qq] = alpha;
                pv4[qq] = p;
            }
            *(float4*)(&pb[wave][lane][0]) = make_float4(pv4[0], pv4[1], pv4[2], pv4[3]);
            __syncthreads();
            float o0 = ou[g * 4 + 0] * al[0];
            float o1 = ou[g * 4 + 1] * al[1];
            float o2 = ou[g * 4 + 2] * al[2];
            float o3 = ou[g * 4 + 3] * al[3];
            for (int jj = 0; jj < 64; ++jj) {
                float4 pj = *(const float4*)(&pb[wave][jj][0]);  // broadcast
                const float vv = Vt[jj][lane];                    // conflict-free (stride 68)
                o0 = fmaf(pj.x, vv, o0);
                o1 = fmaf(pj.y, vv, o1);
                o2 = fmaf(pj.z, vv, o2);
                o3 = fmaf(pj.w, vv, o3);
            }
            ou[g * 4 + 0] = o0;
            ou[g * 4 + 1] = o1;
            ou[g * 4 + 2] = o2;
            ou[g * 4 + 3] = o3;
            __syncthreads();
        }
    }
#pragma unroll
    for (int i = 0; i < 16; ++i) {
        const int q = qb + wave * 16 + i;
        const float o = ou[i] / li[i];
        y[((size_t)(b * 1024 + q)) * 1024 + h * 64 + lane] = f2bf(o);
    }
}

extern "C" void kernel_launch(void* const* d_in, const int* in_sizes, int n_in,
                              void* d_out, int out_size, void* d_ws, size_t ws_size,
                              hipStream_t stream) {
    const float* x      = (const float*)d_in[0];
    const float* qkv_w  = (const float*)d_in[1];
    const float* qkv_b  = (const float*)d_in[2];
    const float* proj_w = (const float*)d_in[3];
    const float* proj_b = (const float*)d_in[4];
    const float* rel    = (const float*)d_in[5];
    float* out = (float*)d_out;

    char* ws = (char*)d_ws;
    unsigned short* xb   = (unsigned short*)(ws);
    unsigned short* wb   = (unsigned short*)(ws + 8388608);
    unsigned short* pwb  = (unsigned short*)(ws + 14680064);
    float* table         = (float*)(ws + 16777216);
    unsigned short* qkvb = (unsigned short*)(ws + 16908288);
    unsigned short* yb   = (unsigned short*)(ws + 42074112);

    cvt_f32_bf16<<<4096, 256, 0, stream>>>(x, xb, 4194304);
    cvt_f32_bf16<<<3072, 256, 0, stream>>>(qkv_w, wb, 3145728);
    cvt_f32_bf16<<<1024, 256, 0, stream>>>(proj_w, pwb, 1048576);
    table_reduce<<<2047, 256, 0, stream>>>(rel, table);
    gemm_bt<0><<<dim3(64, 48), 256, 0, stream>>>(xb, wb, qkv_b, qkvb, nullptr, 4096, 3072, 1024);
    attn_kernel<<<dim3(64, 16), 256, 0, stream>>>(qkvb, table, yb);
    gemm_bt<1><<<dim3(64, 16), 256, 0, stream>>>(yb, pwb, proj_b, nullptr, out, 4096, 1024, 1024);
}

// Round 2
// 232.322 us; speedup vs baseline: 24.6488x; 24.6488x over previous
//
#include <hip/hip_runtime.h>
#include <hip/hip_bf16.h>

// Problem: B=4, T=1024, C=1024, H=16, D=64, MAX_LEN=1024, NPOS=2047
// Pipeline:
//   cvt x,qkv_w,proj_w -> bf16 | table_reduce rel_pos_emb -> (2047,16)
//   gemm_bt<0>: qkv = x @ qkv_w^T + b -> scatter bf16; Q,K as (B,H,T,D), V as (B,H,D,T) (transposed!)
//   attn_mfma: flash causal softmax w/ rel-pos bias, MFMA QK^T and PV -> y (B,T,C) bf16
//   gemm_bt<1>: out = y @ proj_w^T + b -> fp32 d_out
//
// Workspace layout (bytes):
//   xb   @ 0         : 4096x1024 bf16  (8 MB)
//   wb   @ 8388608   : 3072x1024 bf16  (6 MB)
//   pwb  @ 14680064  : 1024x1024 bf16  (2 MB)
//   table@ 16777216  : 2047x16 f32     (128 KB)
//   qkvb @ 16908288  : (3,4,16,64K) bf16 (24 MB)
//   y    @ 42074112  : 4096x1024 bf16  (8 MB)

typedef __bf16 bf16x8 __attribute__((ext_vector_type(8)));
typedef float f32x4 __attribute__((ext_vector_type(4)));

__device__ __forceinline__ float bf2f(unsigned short u) {
    return __uint_as_float(((unsigned)u) << 16);
}
__device__ __forceinline__ unsigned short f2bf(float f) {
    __hip_bfloat16 h = __float2bfloat16(f);
    return *reinterpret_cast<unsigned short*>(&h);
}

// ---------------- fp32 -> bf16 conversion ----------------
__global__ __launch_bounds__(256) void cvt_f32_bf16(const float* __restrict__ in,
                                                    unsigned short* __restrict__ out, int n) {
    int i = (blockIdx.x * 256 + threadIdx.x) * 4;
    if (i < n) {
        float4 v = *(const float4*)(in + i);
        out[i]     = f2bf(v.x);
        out[i + 1] = f2bf(v.y);
        out[i + 2] = f2bf(v.z);
        out[i + 3] = f2bf(v.w);
    }
}

// ---------------- rel_pos_emb (2047,1024) -> table (2047,16) ----------------
__global__ __launch_bounds__(256) void table_reduce(const float* __restrict__ rel,
                                                    float* __restrict__ table) {
    const int p = blockIdx.x;
    const int tid = threadIdx.x, lane = tid & 63, wave = tid >> 6;
    const float* r = rel + (size_t)p * 1024;
    float s[4];
#pragma unroll
    for (int k = 0; k < 4; ++k) s[k] = r[tid + 256 * k];
#pragma unroll
    for (int k = 0; k < 4; ++k) {
        float v = s[k];
        for (int o = 32; o; o >>= 1) v += __shfl_xor(v, o, 64);
        if (lane == 0) table[p * 16 + wave + 4 * k] = v;
    }
}

// ---------------- bf16 MFMA GEMM: C[m,n] = sum_k A[m,k]*B[n,k] + bias[n] ----------------
// EPI=0: scatter bf16 into qkv planes; Q,K planes are [t][d], V plane is [d][t] (transposed
// so the attention PV MFMA can read V^T B-fragments as contiguous ds_read_b128).
// EPI=1: fp32 row-major out.
template <int EPI>
__global__ __launch_bounds__(256) void gemm_bt(const unsigned short* __restrict__ A,
                                               const unsigned short* __restrict__ Bm,
                                               const float* __restrict__ bias,
                                               unsigned short* __restrict__ outb,
                                               float* __restrict__ outf,
                                               int M, int N, int K) {
    __shared__ __attribute__((aligned(16))) unsigned short As[64][40];
    __shared__ __attribute__((aligned(16))) unsigned short Bs[64][40];
    const int bm = blockIdx.x * 64, bn = blockIdx.y * 64;
    const int tid = threadIdx.x, lane = tid & 63, wave = tid >> 6;
    const int wr = wave & 1, wc = wave >> 1;
    const int quad = lane >> 4, lm = lane & 15;
    const int srow = tid >> 2, scol = (tid & 3) * 8;

    f32x4 acc00 = {0.f, 0.f, 0.f, 0.f};
    f32x4 acc01 = {0.f, 0.f, 0.f, 0.f};
    f32x4 acc10 = {0.f, 0.f, 0.f, 0.f};
    f32x4 acc11 = {0.f, 0.f, 0.f, 0.f};

    const unsigned short* Aptr = A + (size_t)(bm + srow) * K + scol;
    const unsigned short* Bptr = Bm + (size_t)(bn + srow) * K + scol;

    for (int kk = 0; kk < K; kk += 32) {
        __syncthreads();
        *(int4*)(&As[srow][scol]) = *(const int4*)(Aptr + kk);
        *(int4*)(&Bs[srow][scol]) = *(const int4*)(Bptr + kk);
        __syncthreads();
        bf16x8 a0 = *(const bf16x8*)(&As[32 * wr + lm][quad * 8]);
        bf16x8 a1 = *(const bf16x8*)(&As[32 * wr + 16 + lm][quad * 8]);
        bf16x8 b0 = *(const bf16x8*)(&Bs[32 * wc + lm][quad * 8]);
        bf16x8 b1 = *(const bf16x8*)(&Bs[32 * wc + 16 + lm][quad * 8]);
        acc00 = __builtin_amdgcn_mfma_f32_16x16x32_bf16(a0, b0, acc00, 0, 0, 0);
        acc01 = __builtin_amdgcn_mfma_f32_16x16x32_bf16(a0, b1, acc01, 0, 0, 0);
        acc10 = __builtin_amdgcn_mfma_f32_16x16x32_bf16(a1, b0, acc10, 0, 0, 0);
        acc11 = __builtin_amdgcn_mfma_f32_16x16x32_bf16(a1, b1, acc11, 0, 0, 0);
    }

    f32x4 accs[2][2] = {{acc00, acc01}, {acc10, acc11}};
#pragma unroll
    for (int r = 0; r < 2; ++r)
#pragma unroll
        for (int c = 0; c < 2; ++c)
#pragma unroll
            for (int i = 0; i < 4; ++i) {
                const int row = bm + 32 * wr + 16 * r + quad * 4 + i;
                const int col = bn + 32 * wc + 16 * c + lm;
                const float v = accs[r][c][i] + bias[col];
                if (EPI == 0) {
                    const int b = row >> 10, t = row & 1023;
                    const int s3 = col >> 10, rem = col & 1023;
                    const int h = rem >> 6, d = rem & 63;
                    const size_t base = (((size_t)s3 * 4 + b) * 16 + h) * 65536;
                    const size_t off = base + (s3 == 2 ? (size_t)d * 1024 + t
                                                       : (size_t)t * 64 + d);
                    outb[off] = f2bf(v);
                } else {
                    outf[(size_t)row * N + col] = v;
                }
            }
}

// ---------------- MFMA flash causal attention w/ rel-pos bias ----------------
// grid (B*H, T/64), block 256 = 4 waves. Wave w owns queries qb+16w..+15
// (one 16-row MFMA stripe). Q A-fragments live in registers for the whole
// kernel. Per 64-key tile: S = QK^T via 8 MFMA (K bf16 in LDS, NT case),
// bias+mask+online-softmax in C-layout registers (row state mi/li[4]
// replicated across each 16-lane quad group; row reductions = 4 shfl_xor),
// P -> per-wave LDS (C-layout -> A-layout round trip), PV via 8 MFMA
// against the pre-transposed V plane. Only 2 barriers per tile (K/V staging).
__global__ __launch_bounds__(256) void attn_mfma(const unsigned short* __restrict__ qkvb,
                                                 const float* __restrict__ table,
                                                 unsigned short* __restrict__ y) {
    const int bh = blockIdx.x, b = bh >> 4, h = bh & 15;
    const int qb = blockIdx.y * 64;
    const int tid = threadIdx.x, lane = tid & 63, wave = tid >> 6;
    const int quad = lane >> 4, lm = lane & 15;

    __shared__ __attribute__((aligned(16))) unsigned short Ks[64][72];      // [j][d]
    __shared__ __attribute__((aligned(16))) unsigned short Vs[64][72];      // [d][j]  (V^T)
    __shared__ __attribute__((aligned(16))) unsigned short Ps[4][16][72];   // per-wave P
    __shared__ float tb[1088];

    const unsigned short* Qg  = qkvb + ((size_t)(b)*16 + h) * 65536;       // [t][d]
    const unsigned short* Kg  = qkvb + ((size_t)(4 + b)*16 + h) * 65536;   // [t][d]
    const unsigned short* Vtg = qkvb + ((size_t)(8 + b)*16 + h) * 65536;   // [d][t]

    // Q fragments (A-layout: A[m=lm][k=quad*8+i]), resident all kernel
    const bf16x8 qf0 = *(const bf16x8*)(Qg + (size_t)(qb + wave * 16 + lm) * 64 + quad * 8);
    const bf16x8 qf1 = *(const bf16x8*)(Qg + (size_t)(qb + wave * 16 + lm) * 64 + 32 + quad * 8);

    // bias-table window: tb[q-j+63] = table[(q-j+1023)*16+h], q-j in [-63, qb+63]
    const int tbn = qb + 127;
    for (int i = tid; i < tbn; i += 256) tb[i] = table[(960 + i) * 16 + h];

    f32x4 oacc[4];
#pragma unroll
    for (int nb = 0; nb < 4; ++nb) oacc[nb] = (f32x4){0.f, 0.f, 0.f, 0.f};
    float mi[4], li[4];
#pragma unroll
    for (int i = 0; i < 4; ++i) { mi[i] = -1e30f; li[i] = 0.f; }

    const int ktiles = qb / 64 + 1;
    for (int kt = 0; kt < ktiles; ++kt) {
        __syncthreads();
        {
            const int r0 = tid >> 3, c0 = (tid & 7) * 8, r1 = r0 + 32;
            *(int4*)&Ks[r0][c0] = *(const int4*)(Kg + (size_t)(kt * 64 + r0) * 64 + c0);
            *(int4*)&Ks[r1][c0] = *(const int4*)(Kg + (size_t)(kt * 64 + r1) * 64 + c0);
            *(int4*)&Vs[r0][c0] = *(const int4*)(Vtg + (size_t)r0 * 1024 + kt * 64 + c0);
            *(int4*)&Vs[r1][c0] = *(const int4*)(Vtg + (size_t)r1 * 1024 + kt * 64 + c0);
        }
        __syncthreads();

        // S = Q K^T  (D[m=q_local][n=j_local], C-layout: row=quad*4+i, col=lm)
        f32x4 s[4];
#pragma unroll
        for (int nb = 0; nb < 4; ++nb) {
            bf16x8 k0 = *(const bf16x8*)(&Ks[nb * 16 + lm][quad * 8]);
            bf16x8 k1 = *(const bf16x8*)(&Ks[nb * 16 + lm][32 + quad * 8]);
            s[nb] = (f32x4){0.f, 0.f, 0.f, 0.f};
            s[nb] = __builtin_amdgcn_mfma_f32_16x16x32_bf16(qf0, k0, s[nb], 0, 0, 0);
            s[nb] = __builtin_amdgcn_mfma_f32_16x16x32_bf16(qf1, k1, s[nb], 0, 0, 0);
        }

        // scale + rel-pos bias + causal mask
        const int qrow0 = qb + wave * 16 + quad * 4;
        const int jbase = kt * 64 + lm;
#pragma unroll
        for (int nb = 0; nb < 4; ++nb)
#pragma unroll
            for (int i = 0; i < 4; ++i) {
                const int q = qrow0 + i, j = jbase + nb * 16;
                const float v = fmaf(s[nb][i], 0.125f, tb[q - j + 63]);
                s[nb][i] = (j <= q) ? v : -1e30f;
            }

        // online softmax (row reductions within 16-lane quad groups)
        float mnew[4], al[4];
#pragma unroll
        for (int i = 0; i < 4; ++i) {
            float mx = fmaxf(fmaxf(s[0][i], s[1][i]), fmaxf(s[2][i], s[3][i]));
            mx = fmaxf(mx, __shfl_xor(mx, 1, 64));
            mx = fmaxf(mx, __shfl_xor(mx, 2, 64));
            mx = fmaxf(mx, __shfl_xor(mx, 4, 64));
            mx = fmaxf(mx, __shfl_xor(mx, 8, 64));
            mnew[i] = fmaxf(mi[i], mx);
            al[i] = __expf(mi[i] - mnew[i]);
            mi[i] = mnew[i];
        }
#pragma unroll
        for (int nb = 0; nb < 4; ++nb)
#pragma unroll
            for (int i = 0; i < 4; ++i) s[nb][i] = __expf(s[nb][i] - mnew[i]);
#pragma unroll
        for (int i = 0; i < 4; ++i) {
            float sm = (s[0][i] + s[1][i]) + (s[2][i] + s[3][i]);
            sm += __shfl_xor(sm, 1, 64);
            sm += __shfl_xor(sm, 2, 64);
            sm += __shfl_xor(sm, 4, 64);
            sm += __shfl_xor(sm, 8, 64);
            li[i] = li[i] * al[i] + sm;
        }

        // P: C-layout regs -> per-wave LDS (bf16), for A-layout re-read
#pragma unroll
        for (int nb = 0; nb < 4; ++nb)
#pragma unroll
            for (int i = 0; i < 4; ++i)
                Ps[wave][quad * 4 + i][nb * 16 + lm] = f2bf(s[nb][i]);

        // rescale O accumulators
#pragma unroll
        for (int nb = 0; nb < 4; ++nb)
#pragma unroll
            for (int i = 0; i < 4; ++i) oacc[nb][i] *= al[i];

        // O += P V   (A = P [q][j], B = V^T [d][j]; both contiguous b128 reads)
        const bf16x8 p0 = *(const bf16x8*)(&Ps[wave][lm][quad * 8]);
        const bf16x8 p1 = *(const bf16x8*)(&Ps[wave][lm][32 + quad * 8]);
#pragma unroll
        for (int nb = 0; nb < 4; ++nb) {
            bf16x8 v0 = *(const bf16x8*)(&Vs[nb * 16 + lm][quad * 8]);
            bf16x8 v1 = *(const bf16x8*)(&Vs[nb * 16 + lm][32 + quad * 8]);
            oacc[nb] = __builtin_amdgcn_mfma_f32_16x16x32_bf16(p0, v0, oacc[nb], 0, 0, 0);
            oacc[nb] = __builtin_amdgcn_mfma_f32_16x16x32_bf16(p1, v1, oacc[nb], 0, 0, 0);
        }
    }

    // epilogue: O / li -> y (B,T,C) bf16
    float inv[4];
#pragma unroll
    for (int i = 0; i < 4; ++i) inv[i] = 1.0f / li[i];
#pragma unroll
    for (int nb = 0; nb < 4; ++nb)
#pragma unroll
        for (int i = 0; i < 4; ++i) {
            const int q = qb + wave * 16 + quad * 4 + i;
            const int d = nb * 16 + lm;
            y[((size_t)(b * 1024 + q)) * 1024 + h * 64 + d] = f2bf(oacc[nb][i] * inv[i]);
        }
}

extern "C" void kernel_launch(void* const* d_in, const int* in_sizes, int n_in,
                              void* d_out, int out_size, void* d_ws, size_t ws_size,
                              hipStream_t stream) {
    const float* x      = (const float*)d_in[0];
    const float* qkv_w  = (const float*)d_in[1];
    const float* qkv_b  = (const float*)d_in[2];
    const float* proj_w = (const float*)d_in[3];
    const float* proj_b = (const float*)d_in[4];
    const float* rel    = (const float*)d_in[5];
    float* out = (float*)d_out;

    char* ws = (char*)d_ws;
    unsigned short* xb   = (unsigned short*)(ws);
    unsigned short* wb   = (unsigned short*)(ws + 8388608);
    unsigned short* pwb  = (unsigned short*)(ws + 14680064);
    float* table         = (float*)(ws + 16777216);
    unsigned short* qkvb = (unsigned short*)(ws + 16908288);
    unsigned short* yb   = (unsigned short*)(ws + 42074112);

    cvt_f32_bf16<<<4096, 256, 0, stream>>>(x, xb, 4194304);
    cvt_f32_bf16<<<3072, 256, 0, stream>>>(qkv_w, wb, 3145728);
    cvt_f32_bf16<<<1024, 256, 0, stream>>>(proj_w, pwb, 1048576);
    table_reduce<<<2047, 256, 0, stream>>>(rel, table);
    gemm_bt<0><<<dim3(64, 48), 256, 0, stream>>>(xb, wb, qkv_b, qkvb, nullptr, 4096, 3072, 1024);
    attn_mfma<<<dim3(64, 16), 256, 0, stream>>>(qkvb, table, yb);
    gemm_bt<1><<<dim3(64, 16), 256, 0, stream>>>(yb, pwb, proj_b, nullptr, out, 4096, 1024, 1024);
}

// Round 3
// 225.952 us; speedup vs baseline: 25.3436x; 1.0282x over previous
//
#include <hip/hip_runtime.h>
#include <hip/hip_bf16.h>

// Problem: B=4, T=1024, C=1024, H=16, D=64, MAX_LEN=1024, NPOS=2047
// Pipeline:
//   cvt x,qkv_w,proj_w -> bf16 | table_reduce rel_pos_emb -> (2047,16)
//   gemm_bt<0>: qkv = x @ qkv_w^T + b -> scatter bf16; Q,K as (B,H,T,D), V as (B,H,D,T)
//   attn_mfma: flash causal softmax w/ rel-pos bias, MFMA QK^T and PV -> y (B,T,C) bf16
//   gemm_bt<1>: out = y @ proj_w^T + b -> fp32 d_out
//
// gemm_bt is the m97-class structure: 128x128 tile, BK=32, 4 waves x (4x4)
// 16x16x32 MFMA tiles, global_load_lds width=16 staging (contiguous LDS
// layout, stride 64B -- DMA lane order fixes the layout, no padding).
//
// Workspace layout (bytes):
//   xb   @ 0         : 4096x1024 bf16  (8 MB)
//   wb   @ 8388608   : 3072x1024 bf16  (6 MB)
//   pwb  @ 14680064  : 1024x1024 bf16  (2 MB)
//   table@ 16777216  : 2047x16 f32     (128 KB)
//   qkvb @ 16908288  : (3,4,16,64K) bf16 (24 MB)
//   y    @ 42074112  : 4096x1024 bf16  (8 MB)

typedef __bf16 bf16x8 __attribute__((ext_vector_type(8)));
typedef float f32x4 __attribute__((ext_vector_type(4)));

__device__ __forceinline__ float bf2f(unsigned short u) {
    return __uint_as_float(((unsigned)u) << 16);
}
__device__ __forceinline__ unsigned short f2bf(float f) {
    __hip_bfloat16 h = __float2bfloat16(f);
    return *reinterpret_cast<unsigned short*>(&h);
}

// async global->LDS, 16B per lane; LDS dest = wave-uniform base + lane*16.
// AS casts via uintptr round-trip (generic->local == low-32 truncation).
__device__ __forceinline__ void gload16(const unsigned short* g, unsigned short* l) {
    __builtin_amdgcn_global_load_lds(
        (const __attribute__((address_space(1))) unsigned int*)(unsigned long long)(const void*)g,
        (__attribute__((address_space(3))) unsigned int*)(unsigned int)(unsigned long long)(void*)l,
        16, 0, 0);
}

// ---------------- fp32 -> bf16 conversion ----------------
__global__ __launch_bounds__(256) void cvt_f32_bf16(const float* __restrict__ in,
                                                    unsigned short* __restrict__ out, int n) {
    int i = (blockIdx.x * 256 + threadIdx.x) * 4;
    if (i < n) {
        float4 v = *(const float4*)(in + i);
        out[i]     = f2bf(v.x);
        out[i + 1] = f2bf(v.y);
        out[i + 2] = f2bf(v.z);
        out[i + 3] = f2bf(v.w);
    }
}

// ---------------- rel_pos_emb (2047,1024) -> table (2047,16) ----------------
__global__ __launch_bounds__(256) void table_reduce(const float* __restrict__ rel,
                                                    float* __restrict__ table) {
    const int p = blockIdx.x;
    const int tid = threadIdx.x, lane = tid & 63, wave = tid >> 6;
    const float* r = rel + (size_t)p * 1024;
    float s[4];
#pragma unroll
    for (int k = 0; k < 4; ++k) s[k] = r[tid + 256 * k];
#pragma unroll
    for (int k = 0; k < 4; ++k) {
        float v = s[k];
        for (int o = 32; o; o >>= 1) v += __shfl_xor(v, o, 64);
        if (lane == 0) table[p * 16 + wave + 4 * k] = v;
    }
}

// ---------------- bf16 MFMA GEMM (m97 structure): C = A B^T + bias ----------------
// 128x128 tile, BK=32. Wave w = (wr=w&1, wc=w>>1) computes 64x64 quadrant as
// 4x4 16x16x32 MFMA tiles. Staging: each wave DMAs rows w*32..w*32+31 of both
// A and B tiles (2 global_load_lds_dwordx4 each). LDS stride 32 shorts (64B),
// contiguous -- fragment ds_read_b128s cover a contiguous 1KB/wave region.
// EPI=0: scatter bf16 into qkv planes; Q,K planes [t][d], V plane [d][t].
// EPI=1: fp32 row-major out.
template <int EPI>
__global__ __launch_bounds__(256) void gemm_bt(const unsigned short* __restrict__ A,
                                               const unsigned short* __restrict__ Bm,
                                               const float* __restrict__ bias,
                                               unsigned short* __restrict__ outb,
                                               float* __restrict__ outf,
                                               int M, int N, int K) {
    __shared__ __attribute__((aligned(16))) unsigned short As[128 * 32];
    __shared__ __attribute__((aligned(16))) unsigned short Bs[128 * 32];
    const int bm = blockIdx.x * 128, bn = blockIdx.y * 128;
    const int tid = threadIdx.x, lane = tid & 63, wave = tid >> 6;
    const int wr = wave & 1, wc = wave >> 1;
    const int quad = lane >> 4, lm = lane & 15;

    // staging addresses: instr covers 16 rows x 64B; lane l -> row l>>2, 16B chunk l&3
    const int srow = wave * 32 + (lane >> 2);
    const int scol = (lane & 3) * 8;
    const unsigned short* Ap = A + (size_t)(bm + srow) * K + scol;
    const unsigned short* Bp = Bm + (size_t)(bn + srow) * K + scol;
    unsigned short* AsD0 = &As[(wave * 32) * 32];
    unsigned short* AsD1 = &As[(wave * 32 + 16) * 32];
    unsigned short* BsD0 = &Bs[(wave * 32) * 32];
    unsigned short* BsD1 = &Bs[(wave * 32 + 16) * 32];

    f32x4 acc[4][4];
#pragma unroll
    for (int r = 0; r < 4; ++r)
#pragma unroll
        for (int c = 0; c < 4; ++c) acc[r][c] = (f32x4){0.f, 0.f, 0.f, 0.f};

    for (int kk = 0; kk < K; kk += 32) {
        __syncthreads();
        gload16(Ap + kk, AsD0);
        gload16(Ap + (size_t)16 * K + kk, AsD1);
        gload16(Bp + kk, BsD0);
        gload16(Bp + (size_t)16 * K + kk, BsD1);
        __syncthreads();

        bf16x8 af[4], bfr[4];
#pragma unroll
        for (int r = 0; r < 4; ++r)
            af[r] = *(const bf16x8*)(&As[(64 * wr + 16 * r + lm) * 32 + quad * 8]);
#pragma unroll
        for (int c = 0; c < 4; ++c)
            bfr[c] = *(const bf16x8*)(&Bs[(64 * wc + 16 * c + lm) * 32 + quad * 8]);
#pragma unroll
        for (int r = 0; r < 4; ++r)
#pragma unroll
            for (int c = 0; c < 4; ++c)
                acc[r][c] = __builtin_amdgcn_mfma_f32_16x16x32_bf16(af[r], bfr[c], acc[r][c], 0, 0, 0);
    }

    // C/D layout: col = lane&15, row = (lane>>4)*4 + reg
#pragma unroll
    for (int r = 0; r < 4; ++r)
#pragma unroll
        for (int c = 0; c < 4; ++c)
#pragma unroll
            for (int i = 0; i < 4; ++i) {
                const int row = bm + 64 * wr + 16 * r + quad * 4 + i;
                const int col = bn + 64 * wc + 16 * c + lm;
                const float v = acc[r][c][i] + bias[col];
                if (EPI == 0) {
                    const int b = row >> 10, t = row & 1023;
                    const int s3 = col >> 10, rem = col & 1023;
                    const int h = rem >> 6, d = rem & 63;
                    const size_t base = (((size_t)s3 * 4 + b) * 16 + h) * 65536;
                    const size_t off = base + (s3 == 2 ? (size_t)d * 1024 + t
                                                       : (size_t)t * 64 + d);
                    outb[off] = f2bf(v);
                } else {
                    outf[(size_t)row * N + col] = v;
                }
            }
}

// ---------------- MFMA flash causal attention w/ rel-pos bias ----------------
__global__ __launch_bounds__(256) void attn_mfma(const unsigned short* __restrict__ qkvb,
                                                 const float* __restrict__ table,
                                                 unsigned short* __restrict__ y) {
    const int bh = blockIdx.x, b = bh >> 4, h = bh & 15;
    const int qb = blockIdx.y * 64;
    const int tid = threadIdx.x, lane = tid & 63, wave = tid >> 6;
    const int quad = lane >> 4, lm = lane & 15;

    __shared__ __attribute__((aligned(16))) unsigned short Ks[64][72];      // [j][d]
    __shared__ __attribute__((aligned(16))) unsigned short Vs[64][72];      // [d][j]  (V^T)
    __shared__ __attribute__((aligned(16))) unsigned short Ps[4][16][72];   // per-wave P
    __shared__ float tb[1088];

    const unsigned short* Qg  = qkvb + ((size_t)(b)*16 + h) * 65536;       // [t][d]
    const unsigned short* Kg  = qkvb + ((size_t)(4 + b)*16 + h) * 65536;   // [t][d]
    const unsigned short* Vtg = qkvb + ((size_t)(8 + b)*16 + h) * 65536;   // [d][t]

    const bf16x8 qf0 = *(const bf16x8*)(Qg + (size_t)(qb + wave * 16 + lm) * 64 + quad * 8);
    const bf16x8 qf1 = *(const bf16x8*)(Qg + (size_t)(qb + wave * 16 + lm) * 64 + 32 + quad * 8);

    const int tbn = qb + 127;
    for (int i = tid; i < tbn; i += 256) tb[i] = table[(960 + i) * 16 + h];

    f32x4 oacc[4];
#pragma unroll
    for (int nb = 0; nb < 4; ++nb) oacc[nb] = (f32x4){0.f, 0.f, 0.f, 0.f};
    float mi[4], li[4];
#pragma unroll
    for (int i = 0; i < 4; ++i) { mi[i] = -1e30f; li[i] = 0.f; }

    const int ktiles = qb / 64 + 1;
    for (int kt = 0; kt < ktiles; ++kt) {
        __syncthreads();
        {
            const int r0 = tid >> 3, c0 = (tid & 7) * 8, r1 = r0 + 32;
            *(int4*)&Ks[r0][c0] = *(const int4*)(Kg + (size_t)(kt * 64 + r0) * 64 + c0);
            *(int4*)&Ks[r1][c0] = *(const int4*)(Kg + (size_t)(kt * 64 + r1) * 64 + c0);
            *(int4*)&Vs[r0][c0] = *(const int4*)(Vtg + (size_t)r0 * 1024 + kt * 64 + c0);
            *(int4*)&Vs[r1][c0] = *(const int4*)(Vtg + (size_t)r1 * 1024 + kt * 64 + c0);
        }
        __syncthreads();

        f32x4 s[4];
#pragma unroll
        for (int nb = 0; nb < 4; ++nb) {
            bf16x8 k0 = *(const bf16x8*)(&Ks[nb * 16 + lm][quad * 8]);
            bf16x8 k1 = *(const bf16x8*)(&Ks[nb * 16 + lm][32 + quad * 8]);
            s[nb] = (f32x4){0.f, 0.f, 0.f, 0.f};
            s[nb] = __builtin_amdgcn_mfma_f32_16x16x32_bf16(qf0, k0, s[nb], 0, 0, 0);
            s[nb] = __builtin_amdgcn_mfma_f32_16x16x32_bf16(qf1, k1, s[nb], 0, 0, 0);
        }

        const int qrow0 = qb + wave * 16 + quad * 4;
        const int jbase = kt * 64 + lm;
#pragma unroll
        for (int nb = 0; nb < 4; ++nb)
#pragma unroll
            for (int i = 0; i < 4; ++i) {
                const int q = qrow0 + i, j = jbase + nb * 16;
                const float v = fmaf(s[nb][i], 0.125f, tb[q - j + 63]);
                s[nb][i] = (j <= q) ? v : -1e30f;
            }

        float mnew[4], al[4];
#pragma unroll
        for (int i = 0; i < 4; ++i) {
            float mx = fmaxf(fmaxf(s[0][i], s[1][i]), fmaxf(s[2][i], s[3][i]));
            mx = fmaxf(mx, __shfl_xor(mx, 1, 64));
            mx = fmaxf(mx, __shfl_xor(mx, 2, 64));
            mx = fmaxf(mx, __shfl_xor(mx, 4, 64));
            mx = fmaxf(mx, __shfl_xor(mx, 8, 64));
            mnew[i] = fmaxf(mi[i], mx);
            al[i] = __expf(mi[i] - mnew[i]);
            mi[i] = mnew[i];
        }
#pragma unroll
        for (int nb = 0; nb < 4; ++nb)
#pragma unroll
            for (int i = 0; i < 4; ++i) s[nb][i] = __expf(s[nb][i] - mnew[i]);
#pragma unroll
        for (int i = 0; i < 4; ++i) {
            float sm = (s[0][i] + s[1][i]) + (s[2][i] + s[3][i]);
            sm += __shfl_xor(sm, 1, 64);
            sm += __shfl_xor(sm, 2, 64);
            sm += __shfl_xor(sm, 4, 64);
            sm += __shfl_xor(sm, 8, 64);
            li[i] = li[i] * al[i] + sm;
        }

#pragma unroll
        for (int nb = 0; nb < 4; ++nb)
#pragma unroll
            for (int i = 0; i < 4; ++i)
                Ps[wave][quad * 4 + i][nb * 16 + lm] = f2bf(s[nb][i]);

#pragma unroll
        for (int nb = 0; nb < 4; ++nb)
#pragma unroll
            for (int i = 0; i < 4; ++i) oacc[nb][i] *= al[i];

        const bf16x8 p0 = *(const bf16x8*)(&Ps[wave][lm][quad * 8]);
        const bf16x8 p1 = *(const bf16x8*)(&Ps[wave][lm][32 + quad * 8]);
#pragma unroll
        for (int nb = 0; nb < 4; ++nb) {
            bf16x8 v0 = *(const bf16x8*)(&Vs[nb * 16 + lm][quad * 8]);
            bf16x8 v1 = *(const bf16x8*)(&Vs[nb * 16 + lm][32 + quad * 8]);
            oacc[nb] = __builtin_amdgcn_mfma_f32_16x16x32_bf16(p0, v0, oacc[nb], 0, 0, 0);
            oacc[nb] = __builtin_amdgcn_mfma_f32_16x16x32_bf16(p1, v1, oacc[nb], 0, 0, 0);
        }
    }

    float inv[4];
#pragma unroll
    for (int i = 0; i < 4; ++i) inv[i] = 1.0f / li[i];
#pragma unroll
    for (int nb = 0; nb < 4; ++nb)
#pragma unroll
        for (int i = 0; i < 4; ++i) {
            const int q = qb + wave * 16 + quad * 4 + i;
            const int d = nb * 16 + lm;
            y[((size_t)(b * 1024 + q)) * 1024 + h * 64 + d] = f2bf(oacc[nb][i] * inv[i]);
        }
}

extern "C" void kernel_launch(void* const* d_in, const int* in_sizes, int n_in,
                              void* d_out, int out_size, void* d_ws, size_t ws_size,
                              hipStream_t stream) {
    const float* x      = (const float*)d_in[0];
    const float* qkv_w  = (const float*)d_in[1];
    const float* qkv_b  = (const float*)d_in[2];
    const float* proj_w = (const float*)d_in[3];
    const float* proj_b = (const float*)d_in[4];
    const float* rel    = (const float*)d_in[5];
    float* out = (float*)d_out;

    char* ws = (char*)d_ws;
    unsigned short* xb   = (unsigned short*)(ws);
    unsigned short* wb   = (unsigned short*)(ws + 8388608);
    unsigned short* pwb  = (unsigned short*)(ws + 14680064);
    float* table         = (float*)(ws + 16777216);
    unsigned short* qkvb = (unsigned short*)(ws + 16908288);
    unsigned short* yb   = (unsigned short*)(ws + 42074112);

    cvt_f32_bf16<<<4096, 256, 0, stream>>>(x, xb, 4194304);
    cvt_f32_bf16<<<3072, 256, 0, stream>>>(qkv_w, wb, 3145728);
    cvt_f32_bf16<<<1024, 256, 0, stream>>>(proj_w, pwb, 1048576);
    table_reduce<<<2047, 256, 0, stream>>>(rel, table);
    gemm_bt<0><<<dim3(32, 24), 256, 0, stream>>>(xb, wb, qkv_b, qkvb, nullptr, 4096, 3072, 1024);
    attn_mfma<<<dim3(64, 16), 256, 0, stream>>>(qkvb, table, yb);
    gemm_bt<1><<<dim3(32, 8), 256, 0, stream>>>(yb, pwb, proj_b, nullptr, out, 4096, 1024, 1024);
}

// Round 4
// 219.888 us; speedup vs baseline: 26.0426x; 1.0276x over previous
//
#include <hip/hip_runtime.h>
#include <hip/hip_bf16.h>

// Problem: B=4, T=1024, C=1024, H=16, D=64, MAX_LEN=1024, NPOS=2047
// Pipeline:
//   cvt x,qkv_w,proj_w -> bf16 | table_reduce rel_pos_emb -> (2047,16)
//   gemm_bt<0>: qkv = x @ qkv_w^T + b -> scatter bf16; Q,K as (B,H,T,D), V as (B,H,D,T)
//   attn_mfma: flash causal softmax w/ rel-pos bias, MFMA QK^T and PV -> y (B,T,C) bf16
//   gemm_bt<1>: out = y @ proj_w^T + b -> fp32 d_out
//
// gemm_bt: 128x128 tile, BK=32, 4 waves x (4x4) 16x16x32 MFMA, REGISTER
// double-buffer prefetch (global->VGPR int4 loads for tile k+1 issued before
// computing tile k; s_waitcnt lands at the ds_write one full compute phase
// later -- avoids the m97 global_load_lds barrier-drain stall that killed
// round 3 at short K). LDS stride 40 shorts (80B): fragment reads 2-way
// conflict only (free).
//
// Workspace layout (bytes):
//   xb   @ 0         : 4096x1024 bf16  (8 MB)
//   wb   @ 8388608   : 3072x1024 bf16  (6 MB)
//   pwb  @ 14680064  : 1024x1024 bf16  (2 MB)
//   table@ 16777216  : 2047x16 f32     (128 KB)
//   qkvb @ 16908288  : (3,4,16,64K) bf16 (24 MB)
//   y    @ 42074112  : 4096x1024 bf16  (8 MB)

typedef __bf16 bf16x8 __attribute__((ext_vector_type(8)));
typedef float f32x4 __attribute__((ext_vector_type(4)));

__device__ __forceinline__ float bf2f(unsigned short u) {
    return __uint_as_float(((unsigned)u) << 16);
}
__device__ __forceinline__ unsigned short f2bf(float f) {
    __hip_bfloat16 h = __float2bfloat16(f);
    return *reinterpret_cast<unsigned short*>(&h);
}

// ---------------- fp32 -> bf16 conversion ----------------
__global__ __launch_bounds__(256) void cvt_f32_bf16(const float* __restrict__ in,
                                                    unsigned short* __restrict__ out, int n) {
    int i = (blockIdx.x * 256 + threadIdx.x) * 4;
    if (i < n) {
        float4 v = *(const float4*)(in + i);
        out[i]     = f2bf(v.x);
        out[i + 1] = f2bf(v.y);
        out[i + 2] = f2bf(v.z);
        out[i + 3] = f2bf(v.w);
    }
}

// ---------------- rel_pos_emb (2047,1024) -> table (2047,16) ----------------
__global__ __launch_bounds__(256) void table_reduce(const float* __restrict__ rel,
                                                    float* __restrict__ table) {
    const int p = blockIdx.x;
    const int tid = threadIdx.x, lane = tid & 63, wave = tid >> 6;
    const float* r = rel + (size_t)p * 1024;
    float s[4];
#pragma unroll
    for (int k = 0; k < 4; ++k) s[k] = r[tid + 256 * k];
#pragma unroll
    for (int k = 0; k < 4; ++k) {
        float v = s[k];
        for (int o = 32; o; o >>= 1) v += __shfl_xor(v, o, 64);
        if (lane == 0) table[p * 16 + wave + 4 * k] = v;
    }
}

// ---------------- bf16 MFMA GEMM: C = A B^T + bias, reg-prefetch dbuf ----------------
// Staging: thread t owns row t>>1 (of both A and B tiles), 32B chunk (t&1)*32B:
// 2 int4 global loads (consecutive-lane pairs cover a 64B row => coalesced-ish),
// 2 ds_write_b128. EPI=0: scatter bf16 into qkv planes (Q,K [t][d], V [d][t]).
// EPI=1: fp32 row-major out.
template <int EPI>
__global__ __launch_bounds__(256) void gemm_bt(const unsigned short* __restrict__ A,
                                               const unsigned short* __restrict__ Bm,
                                               const float* __restrict__ bias,
                                               unsigned short* __restrict__ outb,
                                               float* __restrict__ outf,
                                               int M, int N, int K) {
    __shared__ __attribute__((aligned(16))) unsigned short As[128 * 40];
    __shared__ __attribute__((aligned(16))) unsigned short Bs[128 * 40];
    const int bm = blockIdx.x * 128, bn = blockIdx.y * 128;
    const int tid = threadIdx.x, lane = tid & 63, wave = tid >> 6;
    const int wr = wave & 1, wc = wave >> 1;
    const int quad = lane >> 4, lm = lane & 15;

    const int srow = tid >> 1;        // 0..127
    const int scol = (tid & 1) * 16;  // shorts
    const unsigned short* Ap = A + (size_t)(bm + srow) * K + scol;
    const unsigned short* Bp = Bm + (size_t)(bn + srow) * K + scol;
    unsigned short* AsW = &As[srow * 40 + scol];
    unsigned short* BsW = &Bs[srow * 40 + scol];

    f32x4 acc[4][4];
#pragma unroll
    for (int r = 0; r < 4; ++r)
#pragma unroll
        for (int c = 0; c < 4; ++c) acc[r][c] = (f32x4){0.f, 0.f, 0.f, 0.f};

    // prologue prefetch of tile 0
    int4 pa0 = *(const int4*)(Ap);
    int4 pa1 = *(const int4*)(Ap + 8);
    int4 pb0 = *(const int4*)(Bp);
    int4 pb1 = *(const int4*)(Bp + 8);

    for (int kk = 0; kk < K; kk += 32) {
        // drain prefetch into LDS
        *(int4*)(AsW)     = pa0;
        *(int4*)(AsW + 8) = pa1;
        *(int4*)(BsW)     = pb0;
        *(int4*)(BsW + 8) = pb1;
        __syncthreads();

        // issue prefetch for tile k+1 (in flight across the MFMA block)
        if (kk + 32 < K) {
            pa0 = *(const int4*)(Ap + kk + 32);
            pa1 = *(const int4*)(Ap + kk + 40);
            pb0 = *(const int4*)(Bp + kk + 32);
            pb1 = *(const int4*)(Bp + kk + 40);
        }

        bf16x8 af[4], bfr[4];
#pragma unroll
        for (int r = 0; r < 4; ++r)
            af[r] = *(const bf16x8*)(&As[(64 * wr + 16 * r + lm) * 40 + quad * 8]);
#pragma unroll
        for (int c = 0; c < 4; ++c)
            bfr[c] = *(const bf16x8*)(&Bs[(64 * wc + 16 * c + lm) * 40 + quad * 8]);
#pragma unroll
        for (int r = 0; r < 4; ++r)
#pragma unroll
            for (int c = 0; c < 4; ++c)
                acc[r][c] = __builtin_amdgcn_mfma_f32_16x16x32_bf16(af[r], bfr[c], acc[r][c], 0, 0, 0);
        __syncthreads();
    }

    // C/D layout: col = lane&15, row = (lane>>4)*4 + reg
#pragma unroll
    for (int r = 0; r < 4; ++r)
#pragma unroll
        for (int c = 0; c < 4; ++c)
#pragma unroll
            for (int i = 0; i < 4; ++i) {
                const int row = bm + 64 * wr + 16 * r + quad * 4 + i;
                const int col = bn + 64 * wc + 16 * c + lm;
                const float v = acc[r][c][i] + bias[col];
                if (EPI == 0) {
                    const int b = row >> 10, t = row & 1023;
                    const int s3 = col >> 10, rem = col & 1023;
                    const int h = rem >> 6, d = rem & 63;
                    const size_t base = (((size_t)s3 * 4 + b) * 16 + h) * 65536;
                    const size_t off = base + (s3 == 2 ? (size_t)d * 1024 + t
                                                       : (size_t)t * 64 + d);
                    outb[off] = f2bf(v);
                } else {
                    outf[(size_t)row * N + col] = v;
                }
            }
}

// ---------------- MFMA flash causal attention w/ rel-pos bias ----------------
__global__ __launch_bounds__(256) void attn_mfma(const unsigned short* __restrict__ qkvb,
                                                 const float* __restrict__ table,
                                                 unsigned short* __restrict__ y) {
    const int bh = blockIdx.x, b = bh >> 4, h = bh & 15;
    const int qb = blockIdx.y * 64;
    const int tid = threadIdx.x, lane = tid & 63, wave = tid >> 6;
    const int quad = lane >> 4, lm = lane & 15;

    __shared__ __attribute__((aligned(16))) unsigned short Ks[64][72];      // [j][d]
    __shared__ __attribute__((aligned(16))) unsigned short Vs[64][72];      // [d][j]  (V^T)
    __shared__ __attribute__((aligned(16))) unsigned short Ps[4][16][72];   // per-wave P
    __shared__ float tb[1088];

    const unsigned short* Qg  = qkvb + ((size_t)(b)*16 + h) * 65536;       // [t][d]
    const unsigned short* Kg  = qkvb + ((size_t)(4 + b)*16 + h) * 65536;   // [t][d]
    const unsigned short* Vtg = qkvb + ((size_t)(8 + b)*16 + h) * 65536;   // [d][t]

    const bf16x8 qf0 = *(const bf16x8*)(Qg + (size_t)(qb + wave * 16 + lm) * 64 + quad * 8);
    const bf16x8 qf1 = *(const bf16x8*)(Qg + (size_t)(qb + wave * 16 + lm) * 64 + 32 + quad * 8);

    const int tbn = qb + 127;
    for (int i = tid; i < tbn; i += 256) tb[i] = table[(960 + i) * 16 + h];

    f32x4 oacc[4];
#pragma unroll
    for (int nb = 0; nb < 4; ++nb) oacc[nb] = (f32x4){0.f, 0.f, 0.f, 0.f};
    float mi[4], li[4];
#pragma unroll
    for (int i = 0; i < 4; ++i) { mi[i] = -1e30f; li[i] = 0.f; }

    const int ktiles = qb / 64 + 1;
    for (int kt = 0; kt < ktiles; ++kt) {
        __syncthreads();
        {
            const int r0 = tid >> 3, c0 = (tid & 7) * 8, r1 = r0 + 32;
            *(int4*)&Ks[r0][c0] = *(const int4*)(Kg + (size_t)(kt * 64 + r0) * 64 + c0);
            *(int4*)&Ks[r1][c0] = *(const int4*)(Kg + (size_t)(kt * 64 + r1) * 64 + c0);
            *(int4*)&Vs[r0][c0] = *(const int4*)(Vtg + (size_t)r0 * 1024 + kt * 64 + c0);
            *(int4*)&Vs[r1][c0] = *(const int4*)(Vtg + (size_t)r1 * 1024 + kt * 64 + c0);
        }
        __syncthreads();

        f32x4 s[4];
#pragma unroll
        for (int nb = 0; nb < 4; ++nb) {
            bf16x8 k0 = *(const bf16x8*)(&Ks[nb * 16 + lm][quad * 8]);
            bf16x8 k1 = *(const bf16x8*)(&Ks[nb * 16 + lm][32 + quad * 8]);
            s[nb] = (f32x4){0.f, 0.f, 0.f, 0.f};
            s[nb] = __builtin_amdgcn_mfma_f32_16x16x32_bf16(qf0, k0, s[nb], 0, 0, 0);
            s[nb] = __builtin_amdgcn_mfma_f32_16x16x32_bf16(qf1, k1, s[nb], 0, 0, 0);
        }

        const int qrow0 = qb + wave * 16 + quad * 4;
        const int jbase = kt * 64 + lm;
#pragma unroll
        for (int nb = 0; nb < 4; ++nb)
#pragma unroll
            for (int i = 0; i < 4; ++i) {
                const int q = qrow0 + i, j = jbase + nb * 16;
                const float v = fmaf(s[nb][i], 0.125f, tb[q - j + 63]);
                s[nb][i] = (j <= q) ? v : -1e30f;
            }

        float mnew[4], al[4];
#pragma unroll
        for (int i = 0; i < 4; ++i) {
            float mx = fmaxf(fmaxf(s[0][i], s[1][i]), fmaxf(s[2][i], s[3][i]));
            mx = fmaxf(mx, __shfl_xor(mx, 1, 64));
            mx = fmaxf(mx, __shfl_xor(mx, 2, 64));
            mx = fmaxf(mx, __shfl_xor(mx, 4, 64));
            mx = fmaxf(mx, __shfl_xor(mx, 8, 64));
            mnew[i] = fmaxf(mi[i], mx);
            al[i] = __expf(mi[i] - mnew[i]);
            mi[i] = mnew[i];
        }
#pragma unroll
        for (int nb = 0; nb < 4; ++nb)
#pragma unroll
            for (int i = 0; i < 4; ++i) s[nb][i] = __expf(s[nb][i] - mnew[i]);
#pragma unroll
        for (int i = 0; i < 4; ++i) {
            float sm = (s[0][i] + s[1][i]) + (s[2][i] + s[3][i]);
            sm += __shfl_xor(sm, 1, 64);
            sm += __shfl_xor(sm, 2, 64);
            sm += __shfl_xor(sm, 4, 64);
            sm += __shfl_xor(sm, 8, 64);
            li[i] = li[i] * al[i] + sm;
        }

#pragma unroll
        for (int nb = 0; nb < 4; ++nb)
#pragma unroll
            for (int i = 0; i < 4; ++i)
                Ps[wave][quad * 4 + i][nb * 16 + lm] = f2bf(s[nb][i]);

#pragma unroll
        for (int nb = 0; nb < 4; ++nb)
#pragma unroll
            for (int i = 0; i < 4; ++i) oacc[nb][i] *= al[i];

        const bf16x8 p0 = *(const bf16x8*)(&Ps[wave][lm][quad * 8]);
        const bf16x8 p1 = *(const bf16x8*)(&Ps[wave][lm][32 + quad * 8]);
#pragma unroll
        for (int nb = 0; nb < 4; ++nb) {
            bf16x8 v0 = *(const bf16x8*)(&Vs[nb * 16 + lm][quad * 8]);
            bf16x8 v1 = *(const bf16x8*)(&Vs[nb * 16 + lm][32 + quad * 8]);
            oacc[nb] = __builtin_amdgcn_mfma_f32_16x16x32_bf16(p0, v0, oacc[nb], 0, 0, 0);
            oacc[nb] = __builtin_amdgcn_mfma_f32_16x16x32_bf16(p1, v1, oacc[nb], 0, 0, 0);
        }
    }

    float inv[4];
#pragma unroll
    for (int i = 0; i < 4; ++i) inv[i] = 1.0f / li[i];
#pragma unroll
    for (int nb = 0; nb < 4; ++nb)
#pragma unroll
        for (int i = 0; i < 4; ++i) {
            const int q = qb + wave * 16 + quad * 4 + i;
            const int d = nb * 16 + lm;
            y[((size_t)(b * 1024 + q)) * 1024 + h * 64 + d] = f2bf(oacc[nb][i] * inv[i]);
        }
}

extern "C" void kernel_launch(void* const* d_in, const int* in_sizes, int n_in,
                              void* d_out, int out_size, void* d_ws, size_t ws_size,
                              hipStream_t stream) {
    const float* x      = (const float*)d_in[0];
    const float* qkv_w  = (const float*)d_in[1];
    const float* qkv_b  = (const float*)d_in[2];
    const float* proj_w = (const float*)d_in[3];
    const float* proj_b = (const float*)d_in[4];
    const float* rel    = (const float*)d_in[5];
    float* out = (float*)d_out;

    char* ws = (char*)d_ws;
    unsigned short* xb   = (unsigned short*)(ws);
    unsigned short* wb   = (unsigned short*)(ws + 8388608);
    unsigned short* pwb  = (unsigned short*)(ws + 14680064);
    float* table         = (float*)(ws + 16777216);
    unsigned short* qkvb = (unsigned short*)(ws + 16908288);
    unsigned short* yb   = (unsigned short*)(ws + 42074112);

    cvt_f32_bf16<<<4096, 256, 0, stream>>>(x, xb, 4194304);
    cvt_f32_bf16<<<3072, 256, 0, stream>>>(qkv_w, wb, 3145728);
    cvt_f32_bf16<<<1024, 256, 0, stream>>>(proj_w, pwb, 1048576);
    table_reduce<<<2047, 256, 0, stream>>>(rel, table);
    gemm_bt<0><<<dim3(32, 24), 256, 0, stream>>>(xb, wb, qkv_b, qkvb, nullptr, 4096, 3072, 1024);
    attn_mfma<<<dim3(64, 16), 256, 0, stream>>>(qkvb, table, yb);
    gemm_bt<1><<<dim3(32, 8), 256, 0, stream>>>(yb, pwb, proj_b, nullptr, out, 4096, 1024, 1024);
}